// Round 1
// baseline (538.736 us; speedup 1.0000x reference)
//
#include <hip/hip_runtime.h>
#include <hip/hip_bf16.h>
#include <math.h>

#define B_SZ 8
#define L_SZ 4096
#define D_SZ 1024
#define CHT  64              // scan chunk length
#define NCH  (L_SZ / CHT)    // 64 chunks

typedef __bf16 bf16_t;
typedef bf16_t bf16x8 __attribute__((ext_vector_type(8)));
typedef bf16_t bf16x4 __attribute__((ext_vector_type(4)));
typedef float  f32x4  __attribute__((ext_vector_type(4)));

#define BM 128
#define BN 128
#define BK 32
#define LDK 40   // padded LDS row (bf16 elems): 80B stride -> 2-way bank alias (free)

// C[m,n] = sum_k A[m,k] * W[n,k]   (A: MxK fp32, W: NxK fp32, C: MxN fp32)
// bf16 MFMA with fp32 accumulation; reg-staged fp32->bf16 conversion into LDS.
__global__ __launch_bounds__(256)
void gemm_abt(const float* __restrict__ A, const float* __restrict__ W,
              float* __restrict__ Cc, int M, int N, int K) {
  __shared__ bf16_t As[BM][LDK];
  __shared__ bf16_t Bs[BN][LDK];
  const int tid  = threadIdx.x;
  const int lane = tid & 63;
  const int wave = tid >> 6;
  const int wm = wave >> 1, wn = wave & 1;
  const int fr = lane & 15;          // frag row (A) / col (B,C)
  const int fk = (lane >> 4) * 8;    // frag k offset
  const int brow = blockIdx.y * BM;
  const int bcol = blockIdx.x * BN;

  const int srow = tid >> 1;         // staging row 0..127
  const int scol = (tid & 1) * 16;   // staging col 0 or 16

  f32x4 acc[4][4] = {};

  for (int k0 = 0; k0 < K; k0 += BK) {
    const float* Ap = A + (size_t)(brow + srow) * K + k0 + scol;
    const float* Wp = W + (size_t)(bcol + srow) * K + k0 + scol;
#pragma unroll
    for (int i = 0; i < 4; ++i) {
      f32x4 va = *(const f32x4*)(Ap + i * 4);
      f32x4 vw = *(const f32x4*)(Wp + i * 4);
      bf16x4 ha, hw;
#pragma unroll
      for (int j = 0; j < 4; ++j) { ha[j] = (bf16_t)va[j]; hw[j] = (bf16_t)vw[j]; }
      *(bf16x4*)&As[srow][scol + i * 4] = ha;
      *(bf16x4*)&Bs[srow][scol + i * 4] = hw;
    }
    __syncthreads();
    bf16x8 af[4], bfr[4];
#pragma unroll
    for (int mi = 0; mi < 4; ++mi)
      af[mi] = *(const bf16x8*)&As[wm * 64 + mi * 16 + fr][fk];
#pragma unroll
    for (int ni = 0; ni < 4; ++ni)
      bfr[ni] = *(const bf16x8*)&Bs[wn * 64 + ni * 16 + fr][fk];
#pragma unroll
    for (int mi = 0; mi < 4; ++mi)
#pragma unroll
      for (int ni = 0; ni < 4; ++ni)
        acc[mi][ni] = __builtin_amdgcn_mfma_f32_16x16x32_bf16(af[mi], bfr[ni], acc[mi][ni], 0, 0, 0);
    __syncthreads();
  }

  // epilogue: C/D layout col=lane&15, row=(lane>>4)*4+r  [m89]
#pragma unroll
  for (int mi = 0; mi < 4; ++mi) {
    const int row = brow + wm * 64 + mi * 16 + (lane >> 4) * 4;
#pragma unroll
    for (int ni = 0; ni < 4; ++ni) {
      const int col = bcol + wn * 64 + ni * 16 + fr;
#pragma unroll
      for (int r = 0; r < 4; ++r)
        Cc[(size_t)(row + r) * N + col] = acc[mi][ni][r];
    }
  }
}

// Local (per-chunk) inclusive scan, in-place on xb; writes chunk finals to cf.
__global__ __launch_bounds__(256)
void scan_local_k(float* __restrict__ xb, const float* __restrict__ log_a,
                  float* __restrict__ cf) {
  const int d = blockIdx.x * 256 + threadIdx.x;
  const int c = blockIdx.y;
  const int b = blockIdx.z;
  const float a = expf(log_a[d]);
  const size_t base = ((size_t)(b * L_SZ + c * CHT)) * D_SZ + d;
  float s = 0.f;
  float v[8];
  for (int t0 = 0; t0 < CHT; t0 += 8) {
#pragma unroll
    for (int j = 0; j < 8; ++j) v[j] = xb[base + (size_t)(t0 + j) * D_SZ];
#pragma unroll
    for (int j = 0; j < 8; ++j) {
      s = a * s + v[j];
      xb[base + (size_t)(t0 + j) * D_SZ] = s;
    }
  }
  cf[((size_t)(b * NCH + c)) * D_SZ + d] = s;
}

// Sequential scan over chunk finals with factor a^CHT, in place: F_c -> S_c.
__global__ __launch_bounds__(256)
void scan_carry_k(const float* __restrict__ log_a, float* __restrict__ cf) {
  const int d = blockIdx.x * 256 + threadIdx.x;
  const int b = blockIdx.y;
  const float aT = expf(log_a[d] * (float)CHT);
  float s = 0.f;
  for (int c = 0; c < NCH; ++c) {
    const size_t idx = ((size_t)(b * NCH + c)) * D_SZ + d;
    s = aT * s + cf[idx];
    cf[idx] = s;
  }
}

// state[b, l, d] += a^(t+1) * S_{c-1}[b, d]   for chunks c >= 1
__global__ __launch_bounds__(256)
void scan_apply_k(float* __restrict__ xb, const float* __restrict__ log_a,
                  const float* __restrict__ cf) {
  const int d = blockIdx.x * 256 + threadIdx.x;
  const int l = CHT + blockIdx.y;          // l = 64..4095
  const int b = blockIdx.z;
  const int c = l >> 6;
  const int t = l & (CHT - 1);
  const float p = expf(log_a[d] * (float)(t + 1));
  const size_t idx = ((size_t)(b * L_SZ + l)) * D_SZ + d;
  xb[idx] += p * cf[((size_t)(b * NCH + (c - 1))) * D_SZ + d];
}

// LayerNorm over D=1024, one block per row, 4 elems/thread.
__global__ __launch_bounds__(256)
void ln_k(const float* __restrict__ y, const float* __restrict__ gamma,
          const float* __restrict__ beta, float* __restrict__ out) {
  const size_t row = blockIdx.x;
  const int tid = threadIdx.x;
  f32x4 v = *(const f32x4*)(y + row * D_SZ + tid * 4);
  float s  = v[0] + v[1] + v[2] + v[3];
  float sq = v[0] * v[0] + v[1] * v[1] + v[2] * v[2] + v[3] * v[3];
#pragma unroll
  for (int off = 32; off; off >>= 1) {
    s  += __shfl_down(s, off);
    sq += __shfl_down(sq, off);
  }
  __shared__ float red[8];
  const int wid = tid >> 6;
  if ((tid & 63) == 0) { red[wid] = s; red[4 + wid] = sq; }
  __syncthreads();
  s  = red[0] + red[1] + red[2] + red[3];
  sq = red[4] + red[5] + red[6] + red[7];
  const float mean = s * (1.f / D_SZ);
  const float var  = sq * (1.f / D_SZ) - mean * mean;
  const float inv  = rsqrtf(var + 1e-5f);
  f32x4 g  = *(const f32x4*)(gamma + tid * 4);
  f32x4 bt = *(const f32x4*)(beta  + tid * 4);
  f32x4 o;
#pragma unroll
  for (int j = 0; j < 4; ++j) o[j] = (v[j] - mean) * inv * g[j] + bt[j];
  *(f32x4*)(out + row * D_SZ + tid * 4) = o;
}

extern "C" void kernel_launch(void* const* d_in, const int* in_sizes, int n_in,
                              void* d_out, int out_size, void* d_ws, size_t ws_size,
                              hipStream_t stream) {
  const float* u     = (const float*)d_in[0];
  const float* log_a = (const float*)d_in[1];
  const float* W_b   = (const float*)d_in[2];
  const float* W_c   = (const float*)d_in[3];
  const float* gamma = (const float*)d_in[4];
  const float* beta  = (const float*)d_in[5];
  float* out = (float*)d_out;

  float* xb = (float*)d_ws;                            // B*L*D  (u_b -> states, in place)
  float* y  = xb + (size_t)B_SZ * L_SZ * D_SZ;         // B*L*D
  float* cf = y  + (size_t)B_SZ * L_SZ * D_SZ;         // B*NCH*D chunk finals -> carries

  const int M = B_SZ * L_SZ;
  dim3 gg(D_SZ / BN, M / BM);

  gemm_abt<<<gg, 256, 0, stream>>>(u, W_b, xb, M, D_SZ, D_SZ);
  scan_local_k<<<dim3(D_SZ / 256, NCH, B_SZ), 256, 0, stream>>>(xb, log_a, cf);
  scan_carry_k<<<dim3(D_SZ / 256, B_SZ), 256, 0, stream>>>(log_a, cf);
  scan_apply_k<<<dim3(D_SZ / 256, L_SZ - CHT, B_SZ), 256, 0, stream>>>(xb, log_a, cf);
  gemm_abt<<<gg, 256, 0, stream>>>(xb, W_c, y, M, D_SZ, D_SZ);
  ln_k<<<M, 256, 0, stream>>>(y, gamma, beta, out);
}

// Round 2
// 390.649 us; speedup vs baseline: 1.3791x; 1.3791x over previous
//
#include <hip/hip_runtime.h>
#include <hip/hip_bf16.h>
#include <math.h>

#define B_SZ 8
#define L_SZ 4096
#define D_SZ 1024
#define CHT  64
#define NCH  (L_SZ / CHT)

typedef __bf16 bf16_t;
typedef bf16_t bf16x8 __attribute__((ext_vector_type(8)));
typedef bf16_t bf16x4 __attribute__((ext_vector_type(4)));
typedef float  f32x4  __attribute__((ext_vector_type(4)));

#define BM 128
#define BN 128
#define BK 32

__device__ __forceinline__ void gld16(const void* g, void* l) {
  __builtin_amdgcn_global_load_lds(
      (const __attribute__((address_space(1))) void*)g,
      (__attribute__((address_space(3))) void*)l, 16, 0, 0);
}

// C[m,n] = sum_k A[m,k] * Wt[n,k]; A,Wt bf16 row-major, C fp32.
// m97 structure: linear LDS, global_load_lds x16B, 2-barrier K-loop.
__global__ __launch_bounds__(256)
void gemm_bf16(const bf16_t* __restrict__ A, const bf16_t* __restrict__ Wt,
               float* __restrict__ Cc, int M, int N, int K) {
  __shared__ bf16_t As[BM * BK];
  __shared__ bf16_t Bs[BN * BK];
  const int tid  = threadIdx.x;
  const int lane = tid & 63;
  const int wave = tid >> 6;
  const int wm = wave >> 1, wn = wave & 1;
  const int fr = lane & 15;
  const int fk = (lane >> 4) * 8;
  const int brow = blockIdx.y * BM;
  const int bcol = blockIdx.x * BN;
  const int srow = tid >> 2;          // 0..63
  const int scol = (tid & 3) * 8;     // 0,8,16,24

  const bf16_t* Ag = A  + (size_t)(brow + srow) * K + scol;
  const bf16_t* Bg = Wt + (size_t)(bcol + srow) * K + scol;
  // wave-uniform LDS bases: issue j covers rows j*64..j*64+63
  bf16_t* asb0 = &As[wave * 512];
  bf16_t* asb1 = &As[2048 + wave * 512];
  bf16_t* bsb0 = &Bs[wave * 512];
  bf16_t* bsb1 = &Bs[2048 + wave * 512];

  f32x4 acc[4][4] = {};

  for (int k0 = 0; k0 < K; k0 += BK) {
    gld16(Ag + k0, asb0);
    gld16(Ag + (size_t)64 * K + k0, asb1);
    gld16(Bg + k0, bsb0);
    gld16(Bg + (size_t)64 * K + k0, bsb1);
    __syncthreads();   // compiler drains vmcnt before barrier
    bf16x8 af[4], bfv[4];
#pragma unroll
    for (int mi = 0; mi < 4; ++mi)
      af[mi] = *(const bf16x8*)&As[(wm * 64 + mi * 16 + fr) * BK + fk];
#pragma unroll
    for (int ni = 0; ni < 4; ++ni)
      bfv[ni] = *(const bf16x8*)&Bs[(wn * 64 + ni * 16 + fr) * BK + fk];
#pragma unroll
    for (int mi = 0; mi < 4; ++mi)
#pragma unroll
      for (int ni = 0; ni < 4; ++ni)
        acc[mi][ni] = __builtin_amdgcn_mfma_f32_16x16x32_bf16(af[mi], bfv[ni], acc[mi][ni], 0, 0, 0);
    __syncthreads();
  }

  // C/D layout: col=lane&15, row=(lane>>4)*4+r  [m89]
#pragma unroll
  for (int mi = 0; mi < 4; ++mi) {
    const int row = brow + wm * 64 + mi * 16 + (lane >> 4) * 4;
#pragma unroll
    for (int ni = 0; ni < 4; ++ni) {
      const int col = bcol + wn * 64 + ni * 16 + fr;
#pragma unroll
      for (int r = 0; r < 4; ++r)
        Cc[(size_t)(row + r) * N + col] = acc[mi][ni][r];
    }
  }
}

// fp32 -> bf16 grid-stride convert, 4 elems/thread/iter
__global__ __launch_bounds__(256)
void conv_bf16_k(const float* __restrict__ src, bf16_t* __restrict__ dst, int n) {
  int i = (blockIdx.x * 256 + threadIdx.x) * 4;
  const int stride = gridDim.x * 256 * 4;
  for (; i < n; i += stride) {
    f32x4 v = *(const f32x4*)(src + i);
    bf16x4 h;
#pragma unroll
    for (int j = 0; j < 4; ++j) h[j] = (bf16_t)v[j];
    *(bf16x4*)(dst + i) = h;
  }
}

// pw[t][d] = a_d^(t+1)
__global__ __launch_bounds__(256)
void pow_k(const float* __restrict__ log_a, float* __restrict__ pw) {
  const int t = blockIdx.x;
  const int d = threadIdx.x * 4;
#pragma unroll
  for (int j = 0; j < 4; ++j)
    pw[t * D_SZ + d + j] = expf(log_a[d + j] * (float)(t + 1));
}

// per-chunk inclusive scan in-place on xb (fp32), chunk finals to cf
__global__ __launch_bounds__(256)
void scan_local_k(float* __restrict__ xb, const float* __restrict__ log_a,
                  float* __restrict__ cf) {
  const int d4 = threadIdx.x * 4;
  const int c = blockIdx.x;
  const int b = blockIdx.y;
  f32x4 la = *(const f32x4*)(log_a + d4);
  f32x4 a;
#pragma unroll
  for (int j = 0; j < 4; ++j) a[j] = expf(la[j]);
  const size_t base = ((size_t)(b * L_SZ + c * CHT)) * D_SZ + d4;
  f32x4 s = {0.f, 0.f, 0.f, 0.f};
  for (int t0 = 0; t0 < CHT; t0 += 8) {
    f32x4 v[8];
#pragma unroll
    for (int j = 0; j < 8; ++j) v[j] = *(const f32x4*)(xb + base + (size_t)(t0 + j) * D_SZ);
#pragma unroll
    for (int j = 0; j < 8; ++j) {
      s = a * s + v[j];
      *(f32x4*)(xb + base + (size_t)(t0 + j) * D_SZ) = s;
    }
  }
  *(f32x4*)(cf + ((size_t)(b * NCH + c)) * D_SZ + d4) = s;
}

// sequential scan over chunk finals with factor a^CHT, in place
__global__ __launch_bounds__(256)
void scan_carry_k(const float* __restrict__ log_a, float* __restrict__ cf) {
  const int d = blockIdx.x * 256 + threadIdx.x;
  const int b = blockIdx.y;
  const float aT = expf(log_a[d] * (float)CHT);
  float s = 0.f;
  for (int c = 0; c < NCH; ++c) {
    const size_t idx = ((size_t)(b * NCH + c)) * D_SZ + d;
    s = aT * s + cf[idx];
    cf[idx] = s;
  }
}

// states = xb + a^(t+1)*S_{c-1}; write bf16 for GEMM2. Covers ALL l.
__global__ __launch_bounds__(256)
void scan_apply_k(const float* __restrict__ xb, const float* __restrict__ pw,
                  const float* __restrict__ cf, bf16_t* __restrict__ xs16) {
  const int d4 = threadIdx.x * 4;
  const int l = blockIdx.x;
  const int b = blockIdx.y;
  const int c = l >> 6;
  const int t = l & (CHT - 1);
  const size_t idx = ((size_t)(b * L_SZ + l)) * D_SZ + d4;
  f32x4 s = *(const f32x4*)(xb + idx);
  if (c > 0) {
    f32x4 p  = *(const f32x4*)(pw + t * D_SZ + d4);
    f32x4 cv = *(const f32x4*)(cf + ((size_t)(b * NCH + (c - 1))) * D_SZ + d4);
    s += p * cv;
  }
  bf16x4 h;
#pragma unroll
  for (int j = 0; j < 4; ++j) h[j] = (bf16_t)s[j];
  *(bf16x4*)(xs16 + idx) = h;
}

// LayerNorm over D=1024, one block per row
__global__ __launch_bounds__(256)
void ln_k(const float* __restrict__ y, const float* __restrict__ gamma,
          const float* __restrict__ beta, float* __restrict__ out) {
  const size_t row = blockIdx.x;
  const int tid = threadIdx.x;
  f32x4 v = *(const f32x4*)(y + row * D_SZ + tid * 4);
  float s  = v[0] + v[1] + v[2] + v[3];
  float sq = v[0] * v[0] + v[1] * v[1] + v[2] * v[2] + v[3] * v[3];
#pragma unroll
  for (int off = 32; off; off >>= 1) {
    s  += __shfl_down(s, off);
    sq += __shfl_down(sq, off);
  }
  __shared__ float red[8];
  const int wid = tid >> 6;
  if ((tid & 63) == 0) { red[wid] = s; red[4 + wid] = sq; }
  __syncthreads();
  s  = red[0] + red[1] + red[2] + red[3];
  sq = red[4] + red[5] + red[6] + red[7];
  const float mean = s * (1.f / D_SZ);
  const float var  = sq * (1.f / D_SZ) - mean * mean;
  const float inv  = rsqrtf(var + 1e-5f);
  f32x4 g  = *(const f32x4*)(gamma + tid * 4);
  f32x4 bt = *(const f32x4*)(beta  + tid * 4);
  f32x4 o;
#pragma unroll
  for (int j = 0; j < 4; ++j) o[j] = (v[j] - mean) * inv * g[j] + bt[j];
  *(f32x4*)(out + row * D_SZ + tid * 4) = o;
}

extern "C" void kernel_launch(void* const* d_in, const int* in_sizes, int n_in,
                              void* d_out, int out_size, void* d_ws, size_t ws_size,
                              hipStream_t stream) {
  const float* u     = (const float*)d_in[0];
  const float* log_a = (const float*)d_in[1];
  const float* W_b   = (const float*)d_in[2];
  const float* W_c   = (const float*)d_in[3];
  const float* gamma = (const float*)d_in[4];
  const float* beta  = (const float*)d_in[5];
  float* out = (float*)d_out;

  const size_t NBLD = (size_t)B_SZ * L_SZ * D_SZ;   // 33.5M elems
  float*  xb   = (float*)d_ws;              // fp32 u_b -> states; later aliased as y
  bf16_t* u16  = (bf16_t*)(xb + NBLD);      // bf16 u; later aliased as xs16 (states bf16)
  bf16_t* wb16 = u16 + NBLD;
  bf16_t* wc16 = wb16 + (size_t)D_SZ * D_SZ;
  float*  cf   = (float*)(wc16 + (size_t)D_SZ * D_SZ);   // B*NCH*D chunk carries
  float*  pw   = cf + (size_t)B_SZ * NCH * D_SZ;         // CHT*D power table
  float*  y    = xb;                        // GEMM2 output aliases xb (states fp32 dead)
  bf16_t* xs16 = u16;                       // bf16 states alias u16 (dead after GEMM1)

  const int M = B_SZ * L_SZ;
  dim3 gg(D_SZ / BN, M / BM);

  conv_bf16_k<<<2048, 256, 0, stream>>>(u, u16, (int)NBLD);
  conv_bf16_k<<<512, 256, 0, stream>>>(W_b, wb16, D_SZ * D_SZ);
  conv_bf16_k<<<512, 256, 0, stream>>>(W_c, wc16, D_SZ * D_SZ);
  pow_k<<<CHT, 256, 0, stream>>>(log_a, pw);

  gemm_bf16<<<gg, 256, 0, stream>>>(u16, wb16, xb, M, D_SZ, D_SZ);
  scan_local_k<<<dim3(NCH, B_SZ), 256, 0, stream>>>(xb, log_a, cf);
  scan_carry_k<<<dim3(D_SZ / 256, B_SZ), 256, 0, stream>>>(log_a, cf);
  scan_apply_k<<<dim3(L_SZ, B_SZ), 256, 0, stream>>>(xb, pw, cf, xs16);
  gemm_bf16<<<gg, 256, 0, stream>>>(xs16, wc16, y, M, D_SZ, D_SZ);
  ln_k<<<M, 256, 0, stream>>>(y, gamma, beta, out);
}

// Round 3
// 318.615 us; speedup vs baseline: 1.6909x; 1.2261x over previous
//
#include <hip/hip_runtime.h>
#include <hip/hip_bf16.h>
#include <math.h>

#define B_SZ 8
#define L_SZ 4096
#define D_SZ 1024
#define CHT  64
#define NCH  (L_SZ / CHT)
#define GN   1024
#define GK   1024

typedef __bf16 bf16_t;
typedef bf16_t bf16x8 __attribute__((ext_vector_type(8)));
typedef bf16_t bf16x4 __attribute__((ext_vector_type(4)));
typedef float  f32x4  __attribute__((ext_vector_type(4)));

#define BM 128
#define BN 128
#define BK 32
#define CPAD 132   // padded f32 row for epilogue scan tile

__device__ __forceinline__ void gld16(const void* g, void* l) {
  __builtin_amdgcn_global_load_lds(
      (const __attribute__((address_space(1))) void*)g,
      (__attribute__((address_space(3))) void*)l, 16, 0, 0);
}

// C[m,n] = sum_k A[m,k] * Wt[n,k]; A,Wt bf16 row-major.
// MODE 0: C fp32 + fused per-chunk scan (factor a_d along rows) + chunk finals -> cf
// MODE 1: C bf16 plain store
template<int MODE>
__global__ __launch_bounds__(256)
void gemm_bf16(const bf16_t* __restrict__ A, const bf16_t* __restrict__ Wt,
               void* __restrict__ Cout, const float* __restrict__ log_a,
               float* __restrict__ cf) {
  constexpr int SMEM = (MODE == 0) ? (BM * CPAD * 4) : (BM * BK * 2 + BN * BK * 2);
  __shared__ __align__(16) char smem[SMEM];
  bf16_t* As = (bf16_t*)smem;
  bf16_t* Bs = As + BM * BK;

  const int tid  = threadIdx.x;
  const int lane = tid & 63;
  const int wave = tid >> 6;
  const int wm = wave >> 1, wn = wave & 1;
  const int fr = lane & 15;
  const int fk = (lane >> 4) * 8;

  // XCD-chunked swizzle: 8 col-blocks sharing an A-panel land on one XCD
  const int orig = blockIdx.x;
  const int flat = (orig & 7) * 256 + (orig >> 3);
  const int bx = flat & 7, by = flat >> 3;
  const int brow = by * BM;
  const int bcol = bx * BN;

  const int srow = tid >> 2;          // 0..63
  const int scol = (tid & 3) * 8;     // 0,8,16,24

  const bf16_t* Ag = A  + (size_t)(brow + srow) * GK + scol;
  const bf16_t* Bg = Wt + (size_t)(bcol + srow) * GK + scol;
  bf16_t* asb0 = &As[wave * 512];
  bf16_t* asb1 = &As[2048 + wave * 512];
  bf16_t* bsb0 = &Bs[wave * 512];
  bf16_t* bsb1 = &Bs[2048 + wave * 512];

  f32x4 acc[4][4] = {};

  for (int k0 = 0; k0 < GK; k0 += BK) {
    gld16(Ag + k0, asb0);
    gld16(Ag + (size_t)64 * GK + k0, asb1);
    gld16(Bg + k0, bsb0);
    gld16(Bg + (size_t)64 * GK + k0, bsb1);
    __syncthreads();
    bf16x8 af[4], bfv[4];
#pragma unroll
    for (int mi = 0; mi < 4; ++mi)
      af[mi] = *(const bf16x8*)&As[(wm * 64 + mi * 16 + fr) * BK + fk];
#pragma unroll
    for (int ni = 0; ni < 4; ++ni)
      bfv[ni] = *(const bf16x8*)&Bs[(wn * 64 + ni * 16 + fr) * BK + fk];
#pragma unroll
    for (int mi = 0; mi < 4; ++mi)
#pragma unroll
      for (int ni = 0; ni < 4; ++ni)
        acc[mi][ni] = __builtin_amdgcn_mfma_f32_16x16x32_bf16(af[mi], bfv[ni], acc[mi][ni], 0, 0, 0);
    __syncthreads();
  }

  if constexpr (MODE == 1) {
    bf16_t* C16 = (bf16_t*)Cout;
#pragma unroll
    for (int mi = 0; mi < 4; ++mi) {
      const int row = brow + wm * 64 + mi * 16 + (lane >> 4) * 4;
#pragma unroll
      for (int ni = 0; ni < 4; ++ni) {
        const int col = bcol + wn * 64 + ni * 16 + fr;
#pragma unroll
        for (int r = 0; r < 4; ++r)
          C16[(size_t)(row + r) * GN + col] = (bf16_t)acc[mi][ni][r];
      }
    }
  } else {
    float* Cf = (float*)Cout;
    float* Ct = (float*)smem;   // 128 x CPAD, aliases As/Bs (dead after loop barrier)
    // 1) accumulators -> LDS tile
#pragma unroll
    for (int mi = 0; mi < 4; ++mi) {
      const int row = wm * 64 + mi * 16 + (lane >> 4) * 4;
#pragma unroll
      for (int ni = 0; ni < 4; ++ni) {
        const int col = wn * 64 + ni * 16 + fr;
#pragma unroll
        for (int r = 0; r < 4; ++r)
          Ct[(row + r) * CPAD + col] = acc[mi][ni][r];
      }
    }
    __syncthreads();
    // 2) per-column serial scan over each 64-row chunk (2 chunks per block)
    {
      const int col  = tid & 127;
      const int half = tid >> 7;          // chunk within block
      const int d    = bcol + col;
      const float a  = expf(log_a[d]);
      const int r0   = half * 64;
      float s = 0.f;
      for (int t = 0; t < CHT; ++t) {
        s = a * s + Ct[(r0 + t) * CPAD + col];
        Ct[(r0 + t) * CPAD + col] = s;
      }
      const int b = by >> 5;                       // batch (32 row-blocks per batch)
      const int cg = (by & 31) * 2 + half;         // global chunk index
      cf[((size_t)(b * NCH + cg)) * D_SZ + d] = s;
    }
    __syncthreads();
    // 3) LDS tile -> global (coalesced f32x4)
#pragma unroll
    for (int i = 0; i < 16; ++i) {
      const int idx = i * 256 + tid;       // 0..4095 f32x4 units
      const int row = idx >> 5;
      const int c4  = (idx & 31) * 4;
      *(f32x4*)&Cf[(size_t)(brow + row) * GN + bcol + c4] = *(const f32x4*)&Ct[row * CPAD + c4];
    }
  }
}

// fp32 -> bf16 grid-stride convert
__global__ __launch_bounds__(256)
void conv_bf16_k(const float* __restrict__ src, bf16_t* __restrict__ dst, int n) {
  int i = (blockIdx.x * 256 + threadIdx.x) * 4;
  const int stride = gridDim.x * 256 * 4;
  for (; i < n; i += stride) {
    f32x4 v = *(const f32x4*)(src + i);
    bf16x4 h;
#pragma unroll
    for (int j = 0; j < 4; ++j) h[j] = (bf16_t)v[j];
    *(bf16x4*)(dst + i) = h;
  }
}

// pw[t][d] = a_d^(t+1)
__global__ __launch_bounds__(256)
void pow_k(const float* __restrict__ log_a, float* __restrict__ pw) {
  const int t = blockIdx.x;
  const int d = threadIdx.x * 4;
#pragma unroll
  for (int j = 0; j < 4; ++j)
    pw[t * D_SZ + d + j] = expf(log_a[d + j] * (float)(t + 1));
}

// sequential scan over chunk finals with factor a^CHT, in place
__global__ __launch_bounds__(256)
void scan_carry_k(const float* __restrict__ log_a, float* __restrict__ cf) {
  const int d = blockIdx.x * 256 + threadIdx.x;
  const int b = blockIdx.y;
  const float aT = expf(log_a[d] * (float)CHT);
  float s = 0.f;
  for (int c = 0; c < NCH; ++c) {
    const size_t idx = ((size_t)(b * NCH + c)) * D_SZ + d;
    s = aT * s + cf[idx];
    cf[idx] = s;
  }
}

// states = xb + a^(t+1)*S_{c-1}; write bf16 for GEMM2
__global__ __launch_bounds__(256)
void scan_apply_k(const float* __restrict__ xb, const float* __restrict__ pw,
                  const float* __restrict__ cf, bf16_t* __restrict__ xs16) {
  const int d4 = threadIdx.x * 4;
  const int l = blockIdx.x;
  const int b = blockIdx.y;
  const int c = l >> 6;
  const int t = l & (CHT - 1);
  const size_t idx = ((size_t)(b * L_SZ + l)) * D_SZ + d4;
  f32x4 s = *(const f32x4*)(xb + idx);
  if (c > 0) {
    f32x4 p  = *(const f32x4*)(pw + t * D_SZ + d4);
    f32x4 cv = *(const f32x4*)(cf + ((size_t)(b * NCH + (c - 1))) * D_SZ + d4);
    s += p * cv;
  }
  bf16x4 h;
#pragma unroll
  for (int j = 0; j < 4; ++j) h[j] = (bf16_t)s[j];
  *(bf16x4*)(xs16 + idx) = h;
}

// LayerNorm over D=1024 (bf16 input, fp32 output), one block per row
__global__ __launch_bounds__(256)
void ln_k(const bf16_t* __restrict__ y, const float* __restrict__ gamma,
          const float* __restrict__ beta, float* __restrict__ out) {
  const size_t row = blockIdx.x;
  const int tid = threadIdx.x;
  bf16x4 h = *(const bf16x4*)(y + row * D_SZ + tid * 4);
  float v[4];
#pragma unroll
  for (int j = 0; j < 4; ++j) v[j] = (float)h[j];
  float s  = v[0] + v[1] + v[2] + v[3];
  float sq = v[0] * v[0] + v[1] * v[1] + v[2] * v[2] + v[3] * v[3];
#pragma unroll
  for (int off = 32; off; off >>= 1) {
    s  += __shfl_down(s, off);
    sq += __shfl_down(sq, off);
  }
  __shared__ float red[8];
  const int wid = tid >> 6;
  if ((tid & 63) == 0) { red[wid] = s; red[4 + wid] = sq; }
  __syncthreads();
  s  = red[0] + red[1] + red[2] + red[3];
  sq = red[4] + red[5] + red[6] + red[7];
  const float mean = s * (1.f / D_SZ);
  const float var  = sq * (1.f / D_SZ) - mean * mean;
  const float inv  = rsqrtf(var + 1e-5f);
  f32x4 g  = *(const f32x4*)(gamma + tid * 4);
  f32x4 bt = *(const f32x4*)(beta  + tid * 4);
  f32x4 o;
#pragma unroll
  for (int j = 0; j < 4; ++j) o[j] = (v[j] - mean) * inv * g[j] + bt[j];
  *(f32x4*)(out + row * D_SZ + tid * 4) = o;
}

extern "C" void kernel_launch(void* const* d_in, const int* in_sizes, int n_in,
                              void* d_out, int out_size, void* d_ws, size_t ws_size,
                              hipStream_t stream) {
  const float* u     = (const float*)d_in[0];
  const float* log_a = (const float*)d_in[1];
  const float* W_b   = (const float*)d_in[2];
  const float* W_c   = (const float*)d_in[3];
  const float* gamma = (const float*)d_in[4];
  const float* beta  = (const float*)d_in[5];
  float* out = (float*)d_out;

  const size_t NBLD = (size_t)B_SZ * L_SZ * D_SZ;
  float*  xb   = (float*)d_ws;              // fp32 locally-scanned states; later aliased y16
  bf16_t* u16  = (bf16_t*)(xb + NBLD);      // bf16 u; later aliased xs16
  bf16_t* wb16 = u16 + NBLD;
  bf16_t* wc16 = wb16 + (size_t)D_SZ * D_SZ;
  float*  cf   = (float*)(wc16 + (size_t)D_SZ * D_SZ);
  float*  pw   = cf + (size_t)B_SZ * NCH * D_SZ;
  bf16_t* y16  = (bf16_t*)xb;               // GEMM2 bf16 output aliases xb
  bf16_t* xs16 = u16;

  const int nblk = (B_SZ * L_SZ / BM) * (D_SZ / BN);   // 2048

  conv_bf16_k<<<2048, 256, 0, stream>>>(u, u16, (int)NBLD);
  conv_bf16_k<<<512, 256, 0, stream>>>(W_b, wb16, D_SZ * D_SZ);
  conv_bf16_k<<<512, 256, 0, stream>>>(W_c, wc16, D_SZ * D_SZ);
  pow_k<<<CHT, 256, 0, stream>>>(log_a, pw);

  gemm_bf16<0><<<nblk, 256, 0, stream>>>(u16, wb16, xb, log_a, cf);
  scan_carry_k<<<dim3(D_SZ / 256, B_SZ), 256, 0, stream>>>(log_a, cf);
  scan_apply_k<<<dim3(L_SZ, B_SZ), 256, 0, stream>>>(xb, pw, cf, xs16);
  gemm_bf16<1><<<nblk, 256, 0, stream>>>(xs16, wc16, y16, nullptr, nullptr);
  ln_k<<<B_SZ * L_SZ, 256, 0, stream>>>(y16, gamma, beta, out);
}

// Round 4
// 267.988 us; speedup vs baseline: 2.0103x; 1.1889x over previous
//
#include <hip/hip_runtime.h>
#include <hip/hip_bf16.h>
#include <math.h>

#define B_SZ 8
#define L_SZ 4096
#define D_SZ 1024
#define CHT  64
#define NCH  (L_SZ / CHT)

typedef __bf16 bf16_t;
typedef bf16_t bf16x8 __attribute__((ext_vector_type(8)));
typedef bf16_t bf16x4 __attribute__((ext_vector_type(4)));
typedef float  f32x4  __attribute__((ext_vector_type(4)));

#define BM 256
#define BN 256
#define BK 32
#define NT (1024 / BK)     // 32 K-tiles
#define BUFB 32768         // bytes per staging buffer (A 16K + B 16K)
#define EP_P 68            // epilogue strip padded width (f32 elems), 16B-aligned rows

__device__ __forceinline__ void gld16(const void* g, void* l) {
  __builtin_amdgcn_global_load_lds(
      (const __attribute__((address_space(1))) void*)g,
      (__attribute__((address_space(3))) void*)l, 16, 0, 0);
}

// C[m,n] = sum_k A[m,k]*Wt[n,k]; A,Wt bf16 row-major [.,1024]; C bf16 [.,1024].
// 256x256 tile, 8 waves (2x4), BK=32, 3-buffer counted-vmcnt pipeline,
// XOR-swizzled LDS (pre-swizzled global src + swizzled ds_read).
// MODE 0: fused per-64-chunk scan (factor a_d) in epilogue, chunk finals -> cf.
// MODE 1: plain bf16 store.
template<int MODE>
__global__ __launch_bounds__(512, 2)
void gemm256(const bf16_t* __restrict__ A, const bf16_t* __restrict__ Wt,
             bf16_t* __restrict__ Cg, const float* __restrict__ pw,
             float* __restrict__ cf) {
  __shared__ __align__(16) char smem[98304];   // 3x32KB staging; epilogue strip aliases
  const int tid  = threadIdx.x;
  const int lane = tid & 63;
  const int wave = tid >> 6;
  const int wm = wave >> 2, wn = wave & 3;
  const int fr = lane & 15, g = lane >> 4;

  // XCD-chunked bijective swizzle: 512 blocks = 8 XCDs x 64; each XCD: 16 by x 4 bx
  const int flat = (blockIdx.x & 7) * 64 + (blockIdx.x >> 3);
  const int bx = flat & 3, by = flat >> 2;
  const int brow = by * BM, bcol = bx * BN;

  // ---- staging constants (write side): LDS linear, global source pre-swizzled.
  // LDS[row][c] = global[row][c ^ s(row)], s(row) = (row ^ (row>>2)) & 3 (16B chunks)
  const int rA = lane >> 2, cA = lane & 3;
  const int sS = (rA ^ (lane >> 4)) & 3;
  const int scol = ((cA ^ sS) << 3);             // element offset within 32-elem K-tile
  const bf16_t* a0 = A  + (size_t)(brow + wave * 16 + rA) * 1024 + scol;
  const bf16_t* a1 = a0 + (size_t)128 * 1024;
  const bf16_t* b0 = Wt + (size_t)(bcol + wave * 16 + rA) * 1024 + scol;
  const bf16_t* b1 = b0 + (size_t)128 * 1024;

  // ---- read constants: want global chunk g -> read LDS chunk g ^ s(row)
  const int sR  = (fr ^ (fr >> 2)) & 3;
  const int rch = ((g ^ sR) << 4);
  const int aoffB = (wm * 128 + fr) * 64 + rch;
  const int boffB = (wn * 64 + fr) * 64 + rch;

  f32x4 acc[8][4] = {};

#define STAGE(BU, T) { \
    char* d_ = smem + (BU) * BUFB + wave * 1024; \
    const int ko_ = (T) * BK; \
    gld16(a0 + ko_, d_); \
    gld16(a1 + ko_, d_ + 8192); \
    gld16(b0 + ko_, d_ + 16384); \
    gld16(b1 + ko_, d_ + 24576); \
  }

  STAGE(0, 0)
  STAGE(1, 1)
  asm volatile("s_waitcnt vmcnt(4)" ::: "memory");   // tile 0 resident
  __builtin_amdgcn_s_barrier();
  asm volatile("" ::: "memory");

  int bu = 0, bs = 2;
  for (int t = 0; t < NT; ++t) {
    const char* aB = smem + bu * BUFB;
    const char* bB = aB + 16384;
    bf16x8 af[8], bfv[4];
#pragma unroll
    for (int mi = 0; mi < 8; ++mi) af[mi] = *(const bf16x8*)(aB + aoffB + mi * 1024);
#pragma unroll
    for (int ni = 0; ni < 4; ++ni) bfv[ni] = *(const bf16x8*)(bB + boffB + ni * 1024);
    if (t + 2 < NT) STAGE(bs, t + 2)
    __builtin_amdgcn_s_setprio(1);
#pragma unroll
    for (int mi = 0; mi < 8; ++mi)
#pragma unroll
      for (int ni = 0; ni < 4; ++ni)
        acc[mi][ni] = __builtin_amdgcn_mfma_f32_16x16x32_bf16(af[mi], bfv[ni], acc[mi][ni], 0, 0, 0);
    __builtin_amdgcn_s_setprio(0);
    // tile t+1 must be resident for next iter; keep t+2's 4 loads in flight
    if (t + 2 < NT) asm volatile("s_waitcnt vmcnt(4)" ::: "memory");
    else            asm volatile("s_waitcnt vmcnt(0)" ::: "memory");
    __builtin_amdgcn_s_barrier();
    asm volatile("" ::: "memory");
    bu = (bu == 2) ? 0 : bu + 1;
    bs = (bs == 2) ? 0 : bs + 1;
  }
#undef STAGE

  // ---- epilogue: 4 column-strips of 64; strip LDS [256][EP_P] f32 aliases staging
  __syncthreads();
  float* strip = (float*)smem;
  const int bb  = by >> 4;             // batch
  const int cg0 = (by & 15) * 4;       // first global chunk of this block
#pragma unroll 1
  for (int q = 0; q < 4; ++q) {
    if (wn == q) {
#pragma unroll
      for (int mi = 0; mi < 8; ++mi)
#pragma unroll
        for (int ni = 0; ni < 4; ++ni)
#pragma unroll
          for (int r = 0; r < 4; ++r)
            strip[(wm * 128 + mi * 16 + g * 4 + r) * EP_P + ni * 16 + fr] = acc[mi][ni][r];
    }
    __syncthreads();
    if constexpr (MODE == 0) {
      if (tid < 256) {
        const int col = tid & 63;
        const int ch  = tid >> 6;       // chunk within block; one wave per chunk
        const int d   = bcol + q * 64 + col;
        const float a = pw[d];          // pw[0][d] = a_d
        float s = 0.f;
#pragma unroll 1
        for (int grp = 0; grp < 4; ++grp) {
          float v[16];
#pragma unroll
          for (int u = 0; u < 16; ++u) v[u] = strip[(ch * 64 + grp * 16 + u) * EP_P + col];
#pragma unroll
          for (int u = 0; u < 16; ++u) { s = a * s + v[u]; v[u] = s; }
#pragma unroll
          for (int u = 0; u < 16; ++u) strip[(ch * 64 + grp * 16 + u) * EP_P + col] = v[u];
        }
        cf[((size_t)(bb * NCH + cg0 + ch)) * D_SZ + d] = s;
      }
      __syncthreads();
    }
#pragma unroll
    for (int j = 0; j < 4; ++j) {
      const int u = j * 512 + tid;
      const int row = u >> 3;
      const int cu = (u & 7) * 8;
      f32x4 lo = *(const f32x4*)&strip[row * EP_P + cu];
      f32x4 hi = *(const f32x4*)&strip[row * EP_P + cu + 4];
      bf16x8 h;
#pragma unroll
      for (int jj = 0; jj < 4; ++jj) { h[jj] = (bf16_t)lo[jj]; h[4 + jj] = (bf16_t)hi[jj]; }
      *(bf16x8*)&Cg[(size_t)(brow + row) * 1024 + bcol + q * 64 + cu] = h;
    }
    __syncthreads();
  }
}

// fp32 -> bf16 grid-stride convert
__global__ __launch_bounds__(256)
void conv_bf16_k(const float* __restrict__ src, bf16_t* __restrict__ dst, int n) {
  int i = (blockIdx.x * 256 + threadIdx.x) * 4;
  const int stride = gridDim.x * 256 * 4;
  for (; i < n; i += stride) {
    f32x4 v = *(const f32x4*)(src + i);
    bf16x4 h;
#pragma unroll
    for (int j = 0; j < 4; ++j) h[j] = (bf16_t)v[j];
    *(bf16x4*)(dst + i) = h;
  }
}

// pw[t][d] = a_d^(t+1)
__global__ __launch_bounds__(256)
void pow_k(const float* __restrict__ log_a, float* __restrict__ pw) {
  const int t = blockIdx.x;
  const int d = threadIdx.x * 4;
#pragma unroll
  for (int j = 0; j < 4; ++j)
    pw[t * D_SZ + d + j] = expf(log_a[d + j] * (float)(t + 1));
}

// sequential scan over chunk finals with factor a^CHT, in place
__global__ __launch_bounds__(256)
void scan_carry_k(const float* __restrict__ log_a, float* __restrict__ cf) {
  const int d = blockIdx.x * 256 + threadIdx.x;
  const int b = blockIdx.y;
  const float aT = expf(log_a[d] * (float)CHT);
  float s = 0.f;
  for (int c = 0; c < NCH; ++c) {
    const size_t idx = ((size_t)(b * NCH + c)) * D_SZ + d;
    s = aT * s + cf[idx];
    cf[idx] = s;
  }
}

// states = xb16 + a^(t+1)*S_{c-1}; write bf16 for GEMM2
__global__ __launch_bounds__(256)
void scan_apply_k(const bf16_t* __restrict__ xb16, const float* __restrict__ pw,
                  const float* __restrict__ cf, bf16_t* __restrict__ xs16) {
  const int d4 = threadIdx.x * 4;
  const int l = blockIdx.x;
  const int b = blockIdx.y;
  const int c = l >> 6;
  const int t = l & (CHT - 1);
  const size_t idx = ((size_t)(b * L_SZ + l)) * D_SZ + d4;
  bf16x4 hv = *(const bf16x4*)(xb16 + idx);
  f32x4 s;
#pragma unroll
  for (int j = 0; j < 4; ++j) s[j] = (float)hv[j];
  if (c > 0) {
    f32x4 p  = *(const f32x4*)(pw + t * D_SZ + d4);
    f32x4 cv = *(const f32x4*)(cf + ((size_t)(b * NCH + (c - 1))) * D_SZ + d4);
    s += p * cv;
  }
  bf16x4 h;
#pragma unroll
  for (int j = 0; j < 4; ++j) h[j] = (bf16_t)s[j];
  *(bf16x4*)(xs16 + idx) = h;
}

// LayerNorm over D=1024 (bf16 input, fp32 output), one block per row
__global__ __launch_bounds__(256)
void ln_k(const bf16_t* __restrict__ y, const float* __restrict__ gamma,
          const float* __restrict__ beta, float* __restrict__ out) {
  const size_t row = blockIdx.x;
  const int tid = threadIdx.x;
  bf16x4 h = *(const bf16x4*)(y + row * D_SZ + tid * 4);
  float v[4];
#pragma unroll
  for (int j = 0; j < 4; ++j) v[j] = (float)h[j];
  float s  = v[0] + v[1] + v[2] + v[3];
  float sq = v[0] * v[0] + v[1] * v[1] + v[2] * v[2] + v[3] * v[3];
#pragma unroll
  for (int off = 32; off; off >>= 1) {
    s  += __shfl_down(s, off);
    sq += __shfl_down(sq, off);
  }
  __shared__ float red[8];
  const int wid = tid >> 6;
  if ((tid & 63) == 0) { red[wid] = s; red[4 + wid] = sq; }
  __syncthreads();
  s  = red[0] + red[1] + red[2] + red[3];
  sq = red[4] + red[5] + red[6] + red[7];
  const float mean = s * (1.f / D_SZ);
  const float var  = sq * (1.f / D_SZ) - mean * mean;
  const float inv  = rsqrtf(var + 1e-5f);
  f32x4 gm = *(const f32x4*)(gamma + tid * 4);
  f32x4 bt = *(const f32x4*)(beta  + tid * 4);
  f32x4 o;
#pragma unroll
  for (int j = 0; j < 4; ++j) o[j] = (v[j] - mean) * inv * gm[j] + bt[j];
  *(f32x4*)(out + row * D_SZ + tid * 4) = o;
}

extern "C" void kernel_launch(void* const* d_in, const int* in_sizes, int n_in,
                              void* d_out, int out_size, void* d_ws, size_t ws_size,
                              hipStream_t stream) {
  const float* u     = (const float*)d_in[0];
  const float* log_a = (const float*)d_in[1];
  const float* W_b   = (const float*)d_in[2];
  const float* W_c   = (const float*)d_in[3];
  const float* gamma = (const float*)d_in[4];
  const float* beta  = (const float*)d_in[5];
  float* out = (float*)d_out;

  const size_t NBLD = (size_t)B_SZ * L_SZ * D_SZ;
  bf16_t* u16  = (bf16_t*)d_ws;             // bf16 u; xs16 aliases after GEMM1
  bf16_t* xb16 = u16 + NBLD;                // GEMM1 out (locally scanned, bf16); y16 aliases
  bf16_t* wb16 = xb16 + NBLD;
  bf16_t* wc16 = wb16 + (size_t)D_SZ * D_SZ;
  float*  cf   = (float*)(wc16 + (size_t)D_SZ * D_SZ);
  float*  pw   = cf + (size_t)B_SZ * NCH * D_SZ;
  bf16_t* xs16 = u16;                       // u16 dead after GEMM1
  bf16_t* y16  = xb16;                      // xb16 dead after apply

  const int nblk = (B_SZ * L_SZ / BM) * (D_SZ / BN);   // 512

  conv_bf16_k<<<2048, 256, 0, stream>>>(u, u16, (int)NBLD);
  conv_bf16_k<<<512, 256, 0, stream>>>(W_b, wb16, D_SZ * D_SZ);
  conv_bf16_k<<<512, 256, 0, stream>>>(W_c, wc16, D_SZ * D_SZ);
  pow_k<<<CHT, 256, 0, stream>>>(log_a, pw);

  gemm256<0><<<nblk, 512, 0, stream>>>(u16, wb16, xb16, pw, cf);
  scan_carry_k<<<dim3(D_SZ / 256, B_SZ), 256, 0, stream>>>(log_a, cf);
  scan_apply_k<<<dim3(L_SZ, B_SZ), 256, 0, stream>>>(xb16, pw, cf, xs16);
  gemm256<1><<<nblk, 512, 0, stream>>>(xs16, wc16, y16, nullptr, nullptr);
  ln_k<<<B_SZ * L_SZ, 256, 0, stream>>>(y16, gamma, beta, out);
}

// Round 5
// 267.232 us; speedup vs baseline: 2.0160x; 1.0028x over previous
//
#include <hip/hip_runtime.h>
#include <hip/hip_bf16.h>
#include <math.h>

#define B_SZ 8
#define L_SZ 4096
#define D_SZ 1024
#define CHT  64
#define NCH  (L_SZ / CHT)

typedef __bf16 bf16_t;
typedef bf16_t bf16x8 __attribute__((ext_vector_type(8)));
typedef bf16_t bf16x4 __attribute__((ext_vector_type(4)));
typedef float  f32x4  __attribute__((ext_vector_type(4)));

#define BM 256
#define BN 128
#define BK 64
#define NT (1024 / BK)     // 16 K-tiles
#define BUFB 49152         // bytes per staging buffer: A 32KB + B 16KB
#define EP_P 68            // epilogue strip padded width (f32)

__device__ __forceinline__ void gld16(const void* g, void* l) {
  __builtin_amdgcn_global_load_lds(
      (const __attribute__((address_space(1))) void*)g,
      (__attribute__((address_space(3))) void*)l, 16, 0, 0);
}

// C[m,n] = sum_k A[m,k]*Wt[n,k]; A,Wt bf16 row-major [.,1024]; C bf16.
// 256x128 tile, 8 waves (4Mx2N, wave tile 64x64), BK=64, 3-buffer counted-vmcnt
// pipeline, 3-bit XOR chunk swizzle (pre-swizzled global src + swizzled ds_read):
// LDS[row][ch] = global[row][ch ^ (row&7)]  (16B chunks, 8 per 128B row).
// MODE 0: fused per-64-chunk scan in epilogue, chunk finals -> cf.
// MODE 1: plain bf16 store.
template<int MODE>
__global__ __launch_bounds__(512, 2)
void gemm256(const bf16_t* __restrict__ A, const bf16_t* __restrict__ Wt,
             bf16_t* __restrict__ Cg, const float* __restrict__ pw,
             float* __restrict__ cf) {
  __shared__ __align__(16) char smem[3 * BUFB];   // 144KB; epilogue strip aliases
  const int tid  = threadIdx.x;
  const int lane = tid & 63;
  const int wave = tid >> 6;
  const int wm = wave >> 1, wn = wave & 1;
  const int fr = lane & 15, g = lane >> 4;

  // XCD-chunked bijective swizzle: 1024 blocks = 8 XCDs x 128; per XCD bx fastest
  const int flat = (blockIdx.x & 7) * 128 + (blockIdx.x >> 3);
  const int bx = flat & 7, by = flat >> 3;
  const int brow = by * BM, bcol = bx * BN;

  // ---- staging (write side): LDS linear dest, global source chunk-swizzled
  const int sr = lane >> 3;             // sub-row 0..7
  const int sc = (lane & 7) ^ sr;       // swizzled 16B chunk
  const bf16_t* a0 = A  + (size_t)(brow + wave * 8 + sr) * 1024 + sc * 8;
  const bf16_t* b0 = Wt + (size_t)(bcol + wave * 8 + sr) * 1024 + sc * 8;

  // ---- read side: global chunk c of row r lives at LDS chunk c^(r&7); r&7 == fr&7
  const int c0 = ((g)     ^ (fr & 7)) << 4;     // kstep 0 chunk byte offset
  const int c1 = ((4 + g) ^ (fr & 7)) << 4;     // kstep 1
  const int arowB = (wm * 64 + fr) * 128;       // + mi*2048
  const int browB = (wn * 64 + fr) * 128;       // + ni*2048 (within B region)

  f32x4 acc[4][4] = {};

#define STAGE(BU, T) { \
    char* d_ = smem + (BU) * BUFB + wave * 1024; \
    const size_t ko_ = (size_t)(T) * BK; \
    gld16(a0 + ko_, d_); \
    gld16(a0 + (size_t)64 * 1024 + ko_, d_ + 8192); \
    gld16(a0 + (size_t)128 * 1024 + ko_, d_ + 16384); \
    gld16(a0 + (size_t)192 * 1024 + ko_, d_ + 24576); \
    gld16(b0 + ko_, d_ + 32768); \
    gld16(b0 + (size_t)64 * 1024 + ko_, d_ + 40960); \
  }

  STAGE(0, 0)
  STAGE(1, 1)
  asm volatile("s_waitcnt vmcnt(6)" ::: "memory");   // tile 0 resident
  __builtin_amdgcn_s_barrier();
  asm volatile("" ::: "memory");

  int bu = 0, bs = 2;
  for (int t = 0; t < NT; ++t) {
    const char* aB = smem + bu * BUFB;
    const char* bB = aB + 32768;
    bf16x8 af[4][2], bfv[4][2];
#pragma unroll
    for (int mi = 0; mi < 4; ++mi) {
      af[mi][0] = *(const bf16x8*)(aB + arowB + mi * 2048 + c0);
      af[mi][1] = *(const bf16x8*)(aB + arowB + mi * 2048 + c1);
    }
#pragma unroll
    for (int ni = 0; ni < 4; ++ni) {
      bfv[ni][0] = *(const bf16x8*)(bB + browB + ni * 2048 + c0);
      bfv[ni][1] = *(const bf16x8*)(bB + browB + ni * 2048 + c1);
    }
    if (t + 2 < NT) STAGE(bs, t + 2)
    __builtin_amdgcn_s_setprio(1);
#pragma unroll
    for (int mi = 0; mi < 4; ++mi)
#pragma unroll
      for (int ni = 0; ni < 4; ++ni) {
        acc[mi][ni] = __builtin_amdgcn_mfma_f32_16x16x32_bf16(af[mi][0], bfv[ni][0], acc[mi][ni], 0, 0, 0);
        acc[mi][ni] = __builtin_amdgcn_mfma_f32_16x16x32_bf16(af[mi][1], bfv[ni][1], acc[mi][ni], 0, 0, 0);
      }
    __builtin_amdgcn_s_setprio(0);
    if (t + 2 < NT) asm volatile("s_waitcnt vmcnt(6)" ::: "memory");
    else            asm volatile("s_waitcnt vmcnt(0)" ::: "memory");
    __builtin_amdgcn_s_barrier();
    asm volatile("" ::: "memory");
    bu = (bu == 2) ? 0 : bu + 1;
    bs = (bs == 2) ? 0 : bs + 1;
  }
#undef STAGE

  // ---- epilogue: 2 column-strips of 64; strip LDS [256][EP_P] f32 aliases staging
  __syncthreads();
  float* strip = (float*)smem;
  const int bb  = by >> 4;             // batch (16 row-blocks per batch)
  const int cg0 = (by & 15) * 4;       // first global chunk of this block
#pragma unroll 1
  for (int q = 0; q < 2; ++q) {
    if (wn == q) {
#pragma unroll
      for (int mi = 0; mi < 4; ++mi)
#pragma unroll
        for (int ni = 0; ni < 4; ++ni)
#pragma unroll
          for (int r = 0; r < 4; ++r)
            strip[(wm * 64 + mi * 16 + g * 4 + r) * EP_P + ni * 16 + fr] = acc[mi][ni][r];
    }
    __syncthreads();
    if constexpr (MODE == 0) {
      if (tid < 256) {
        const int col = tid & 63;
        const int ch  = tid >> 6;       // chunk 0..3; one wave per chunk
        const int d   = bcol + q * 64 + col;
        const float a = pw[d];          // pw[0][d] = a_d
        float s = 0.f;
#pragma unroll 1
        for (int grp = 0; grp < 4; ++grp) {
          float v[16];
#pragma unroll
          for (int u = 0; u < 16; ++u) v[u] = strip[(ch * 64 + grp * 16 + u) * EP_P + col];
#pragma unroll
          for (int u = 0; u < 16; ++u) { s = a * s + v[u]; v[u] = s; }
#pragma unroll
          for (int u = 0; u < 16; ++u) strip[(ch * 64 + grp * 16 + u) * EP_P + col] = v[u];
        }
        cf[((size_t)(bb * NCH + cg0 + ch)) * D_SZ + d] = s;
      }
      __syncthreads();
    }
#pragma unroll
    for (int j = 0; j < 4; ++j) {
      const int u = j * 512 + tid;
      const int row = u >> 3;
      const int cu = (u & 7) * 8;
      f32x4 lo = *(const f32x4*)&strip[row * EP_P + cu];
      f32x4 hi = *(const f32x4*)&strip[row * EP_P + cu + 4];
      bf16x8 h;
#pragma unroll
      for (int jj = 0; jj < 4; ++jj) { h[jj] = (bf16_t)lo[jj]; h[4 + jj] = (bf16_t)hi[jj]; }
      *(bf16x8*)&Cg[(size_t)(brow + row) * 1024 + bcol + q * 64 + cu] = h;
    }
    __syncthreads();
  }
}

// fp32 -> bf16 grid-stride convert
__global__ __launch_bounds__(256)
void conv_bf16_k(const float* __restrict__ src, bf16_t* __restrict__ dst, int n) {
  int i = (blockIdx.x * 256 + threadIdx.x) * 4;
  const int stride = gridDim.x * 256 * 4;
  for (; i < n; i += stride) {
    f32x4 v = *(const f32x4*)(src + i);
    bf16x4 h;
#pragma unroll
    for (int j = 0; j < 4; ++j) h[j] = (bf16_t)v[j];
    *(bf16x4*)(dst + i) = h;
  }
}

// pw[t][d] = a_d^(t+1)
__global__ __launch_bounds__(256)
void pow_k(const float* __restrict__ log_a, float* __restrict__ pw) {
  const int t = blockIdx.x;
  const int d = threadIdx.x * 4;
#pragma unroll
  for (int j = 0; j < 4; ++j)
    pw[t * D_SZ + d + j] = expf(log_a[d + j] * (float)(t + 1));
}

// sequential scan over chunk finals with factor a^CHT, in place
__global__ __launch_bounds__(256)
void scan_carry_k(const float* __restrict__ log_a, float* __restrict__ cf) {
  const int d = blockIdx.x * 256 + threadIdx.x;
  const int b = blockIdx.y;
  const float aT = expf(log_a[d] * (float)CHT);
  float s = 0.f;
  for (int c = 0; c < NCH; ++c) {
    const size_t idx = ((size_t)(b * NCH + c)) * D_SZ + d;
    s = aT * s + cf[idx];
    cf[idx] = s;
  }
}

// states = xb16 + a^(t+1)*S_{c-1}; write bf16 for GEMM2
__global__ __launch_bounds__(128)
void scan_apply_k(const bf16_t* __restrict__ xb16, const float* __restrict__ pw,
                  const float* __restrict__ cf, bf16_t* __restrict__ xs16) {
  const int d8 = threadIdx.x * 8;
  const int l = blockIdx.x;
  const int b = blockIdx.y;
  const int c = l >> 6;
  const int t = l & (CHT - 1);
  const size_t idx = ((size_t)(b * L_SZ + l)) * D_SZ + d8;
  bf16x8 hv = *(const bf16x8*)(xb16 + idx);
  float s[8];
#pragma unroll
  for (int j = 0; j < 8; ++j) s[j] = (float)hv[j];
  if (c > 0) {
    f32x4 p0  = *(const f32x4*)(pw + t * D_SZ + d8);
    f32x4 p1  = *(const f32x4*)(pw + t * D_SZ + d8 + 4);
    const float* cb = cf + ((size_t)(b * NCH + (c - 1))) * D_SZ + d8;
    f32x4 v0 = *(const f32x4*)cb;
    f32x4 v1 = *(const f32x4*)(cb + 4);
#pragma unroll
    for (int j = 0; j < 4; ++j) { s[j] += p0[j] * v0[j]; s[4 + j] += p1[j] * v1[j]; }
  }
  bf16x8 h;
#pragma unroll
  for (int j = 0; j < 8; ++j) h[j] = (bf16_t)s[j];
  *(bf16x8*)(xs16 + idx) = h;
}

// LayerNorm over D=1024 (bf16 input, fp32 output), one block per row
__global__ __launch_bounds__(256)
void ln_k(const bf16_t* __restrict__ y, const float* __restrict__ gamma,
          const float* __restrict__ beta, float* __restrict__ out) {
  const size_t row = blockIdx.x;
  const int tid = threadIdx.x;
  bf16x4 h = *(const bf16x4*)(y + row * D_SZ + tid * 4);
  float v[4];
#pragma unroll
  for (int j = 0; j < 4; ++j) v[j] = (float)h[j];
  float s  = v[0] + v[1] + v[2] + v[3];
  float sq = v[0] * v[0] + v[1] * v[1] + v[2] * v[2] + v[3] * v[3];
#pragma unroll
  for (int off = 32; off; off >>= 1) {
    s  += __shfl_down(s, off);
    sq += __shfl_down(sq, off);
  }
  __shared__ float red[8];
  const int wid = tid >> 6;
  if ((tid & 63) == 0) { red[wid] = s; red[4 + wid] = sq; }
  __syncthreads();
  s  = red[0] + red[1] + red[2] + red[3];
  sq = red[4] + red[5] + red[6] + red[7];
  const float mean = s * (1.f / D_SZ);
  const float var  = sq * (1.f / D_SZ) - mean * mean;
  const float inv  = rsqrtf(var + 1e-5f);
  f32x4 gm = *(const f32x4*)(gamma + tid * 4);
  f32x4 bt = *(const f32x4*)(beta  + tid * 4);
  f32x4 o;
#pragma unroll
  for (int j = 0; j < 4; ++j) o[j] = (v[j] - mean) * inv * gm[j] + bt[j];
  *(f32x4*)(out + row * D_SZ + tid * 4) = o;
}

extern "C" void kernel_launch(void* const* d_in, const int* in_sizes, int n_in,
                              void* d_out, int out_size, void* d_ws, size_t ws_size,
                              hipStream_t stream) {
  const float* u     = (const float*)d_in[0];
  const float* log_a = (const float*)d_in[1];
  const float* W_b   = (const float*)d_in[2];
  const float* W_c   = (const float*)d_in[3];
  const float* gamma = (const float*)d_in[4];
  const float* beta  = (const float*)d_in[5];
  float* out = (float*)d_out;

  const size_t NBLD = (size_t)B_SZ * L_SZ * D_SZ;
  bf16_t* u16  = (bf16_t*)d_ws;             // bf16 u; xs16 aliases after GEMM1
  bf16_t* xb16 = u16 + NBLD;                // GEMM1 out (locally scanned); y16 aliases
  bf16_t* wb16 = xb16 + NBLD;
  bf16_t* wc16 = wb16 + (size_t)D_SZ * D_SZ;
  float*  cf   = (float*)(wc16 + (size_t)D_SZ * D_SZ);
  float*  pw   = cf + (size_t)B_SZ * NCH * D_SZ;
  bf16_t* xs16 = u16;                       // u16 dead after GEMM1
  bf16_t* y16  = xb16;                      // xb16 dead after apply

  const int nblk = (B_SZ * L_SZ / BM) * (D_SZ / BN);   // 1024

  conv_bf16_k<<<2048, 256, 0, stream>>>(u, u16, (int)NBLD);
  conv_bf16_k<<<512, 256, 0, stream>>>(W_b, wb16, D_SZ * D_SZ);
  conv_bf16_k<<<512, 256, 0, stream>>>(W_c, wc16, D_SZ * D_SZ);
  pow_k<<<CHT, 256, 0, stream>>>(log_a, pw);

  gemm256<0><<<nblk, 512, 0, stream>>>(u16, wb16, xb16, pw, cf);
  scan_carry_k<<<dim3(D_SZ / 256, B_SZ), 256, 0, stream>>>(log_a, cf);
  scan_apply_k<<<dim3(L_SZ, B_SZ), 128, 0, stream>>>(xb16, pw, cf, xs16);
  gemm256<1><<<nblk, 512, 0, stream>>>(xs16, wc16, y16, nullptr, nullptr);
  ln_k<<<B_SZ * L_SZ, 256, 0, stream>>>(y16, gamma, beta, out);
}